// Round 1
// baseline (16.686 us; speedup 1.0000x reference)
//
#include <hip/hip_runtime.h>
#include <hip/hip_bf16.h>

// out[i, d] = W[d, idx[i]] + b[d]   (one-hot(idx) @ W^T + b)
// B=16384, ENV_NUM=8192, EMB_DIM=128 — but derived from in_sizes for safety.

__global__ void __launch_bounds__(256) onehot_linear_kernel(
    const int* __restrict__ idx,
    const float* __restrict__ W,     // [EMB, ENV] row-major
    const float* __restrict__ bias,  // [EMB]
    float* __restrict__ out,         // [B, EMB]
    int B, int ENV, int EMB) {
    // one thread per (row i, group of 4 consecutive d)
    const int groups_per_row = EMB >> 2;               // 32 for EMB=128
    int t = blockIdx.x * blockDim.x + threadIdx.x;
    int total = B * groups_per_row;
    if (t >= total) return;

    int i  = t / groups_per_row;
    int g  = t - i * groups_per_row;
    int d  = g << 2;
    int c  = idx[i];

    const float* wcol = W + (size_t)d * ENV + c;
    float4 o;
    o.x = wcol[0 * (size_t)ENV] + bias[d + 0];
    o.y = wcol[1 * (size_t)ENV] + bias[d + 1];
    o.z = wcol[2 * (size_t)ENV] + bias[d + 2];
    o.w = wcol[3 * (size_t)ENV] + bias[d + 3];

    reinterpret_cast<float4*>(out)[(size_t)i * groups_per_row + g] = o;
}

extern "C" void kernel_launch(void* const* d_in, const int* in_sizes, int n_in,
                              void* d_out, int out_size, void* d_ws, size_t ws_size,
                              hipStream_t stream) {
    const int*   idx  = (const int*)d_in[0];
    const float* W    = (const float*)d_in[1];
    const float* bias = (const float*)d_in[2];
    float*       out  = (float*)d_out;

    const int B   = in_sizes[0];
    const int EMB = in_sizes[2];
    const int ENV = in_sizes[1] / EMB;

    const int groups_per_row = EMB / 4;
    const int total  = B * groups_per_row;
    const int block  = 256;
    const int grid   = (total + block - 1) / block;

    onehot_linear_kernel<<<grid, block, 0, stream>>>(idx, W, bias, out, B, ENV, EMB);
}

// Round 2
// 14.003 us; speedup vs baseline: 1.1916x; 1.1916x over previous
//
#include <hip/hip_runtime.h>
#include <hip/hip_bf16.h>

// out[i, d] = W[d, idx[i]] + b[d]   (one-hot(idx) @ W^T + b)
// Strategy: Wt[c][d] = W[d][c] + b[d] staged in d_ws (coalesced LDS-tiled
// transpose, bias fused), then out[i][:] = Wt[idx[i]][:] as a pure
// coalesced float4 row copy — eliminates the 32KB-stride column scatter.

__global__ void __launch_bounds__(256) transpose_bias_kernel(
    const float* __restrict__ W,     // [EMB][ENV]
    const float* __restrict__ bias,  // [EMB]
    float* __restrict__ Wt,          // [ENV][EMB]
    int ENV, int EMB) {
    __shared__ float tile[32][33];   // +1 pad: conflict-free both phases
    const int c0 = blockIdx.x * 32;
    const int d0 = blockIdx.y * 32;
    const int tx = threadIdx.x;      // 0..31
    const int ty = threadIdx.y;      // 0..7

    #pragma unroll
    for (int r = ty; r < 32; r += 8)                 // tile[dLocal][cLocal]
        tile[r][tx] = W[(size_t)(d0 + r) * ENV + (c0 + tx)];
    __syncthreads();

    const float bv = bias[d0 + tx];
    #pragma unroll
    for (int r = ty; r < 32; r += 8)                 // Wt[c][d] = tile[d][c] + b[d]
        Wt[(size_t)(c0 + r) * EMB + (d0 + tx)] = tile[tx][r] + bv;
}

__global__ void __launch_bounds__(256) gather_rows_kernel(
    const int* __restrict__ idx,
    const float* __restrict__ Wt,    // [ENV][EMB], bias already fused
    float* __restrict__ out,         // [B][EMB]
    int B, int EMB4) {               // EMB4 = EMB/4
    int t = blockIdx.x * blockDim.x + threadIdx.x;
    int total = B * EMB4;
    if (t >= total) return;
    int i = t / EMB4;
    int g = t - i * EMB4;
    int c = idx[i];
    reinterpret_cast<float4*>(out)[(size_t)t] =
        reinterpret_cast<const float4*>(Wt)[(size_t)c * EMB4 + g];
}

// Fallback (ws too small): direct gather from W with bias add.
__global__ void __launch_bounds__(256) onehot_linear_direct_kernel(
    const int* __restrict__ idx, const float* __restrict__ W,
    const float* __restrict__ bias, float* __restrict__ out,
    int B, int ENV, int EMB) {
    const int groups_per_row = EMB >> 2;
    int t = blockIdx.x * blockDim.x + threadIdx.x;
    int total = B * groups_per_row;
    if (t >= total) return;
    int i = t / groups_per_row;
    int g = t - i * groups_per_row;
    int d = g << 2;
    int c = idx[i];
    const float* wcol = W + (size_t)d * ENV + c;
    float4 o;
    o.x = wcol[0 * (size_t)ENV] + bias[d + 0];
    o.y = wcol[1 * (size_t)ENV] + bias[d + 1];
    o.z = wcol[2 * (size_t)ENV] + bias[d + 2];
    o.w = wcol[3 * (size_t)ENV] + bias[d + 3];
    reinterpret_cast<float4*>(out)[(size_t)i * groups_per_row + g] = o;
}

extern "C" void kernel_launch(void* const* d_in, const int* in_sizes, int n_in,
                              void* d_out, int out_size, void* d_ws, size_t ws_size,
                              hipStream_t stream) {
    const int*   idx  = (const int*)d_in[0];
    const float* W    = (const float*)d_in[1];
    const float* bias = (const float*)d_in[2];
    float*       out  = (float*)d_out;

    const int B   = in_sizes[0];
    const int EMB = in_sizes[2];
    const int ENV = in_sizes[1] / EMB;

    const size_t wt_bytes = (size_t)ENV * EMB * sizeof(float);

    if (ws_size >= wt_bytes && (EMB % 32 == 0) && (ENV % 32 == 0)) {
        float* Wt = (float*)d_ws;

        dim3 tb(32, 8);
        dim3 tg(ENV / 32, EMB / 32);
        transpose_bias_kernel<<<tg, tb, 0, stream>>>(W, bias, Wt, ENV, EMB);

        const int EMB4  = EMB / 4;
        const int total = B * EMB4;
        const int block = 256;
        const int grid  = (total + block - 1) / block;
        gather_rows_kernel<<<grid, block, 0, stream>>>(idx, Wt, out, B, EMB4);
    } else {
        const int groups_per_row = EMB / 4;
        const int total = B * groups_per_row;
        const int block = 256;
        const int grid  = (total + block - 1) / block;
        onehot_linear_direct_kernel<<<grid, block, 0, stream>>>(idx, W, bias, out, B, ENV, EMB);
    }
}